// Round 6
// baseline (233.423 us; speedup 1.0000x reference)
//
#include <hip/hip_runtime.h>

#define NF 128
#define OUTF 64

// mark bits
#define M2 1
#define M1 2
#define M0 4

// capacity caps (expected ~13 / ~180 / ~2600 nodes; huge slack)
#define CAP_F2 2048
#define CAP_E3 4096
#define CAP_F1 32768
#define CAP_E2 65536
#define CAP_F0 131072
#define CAP_E1 262144

// cnt[0]=F2, cnt[1]=E3, cnt[2]=F1, cnt[3]=E2, cnt[4]=F0, cnt[5]=E1
// bar = cnt+64: per-barrier slot of 4096 ints (16KB):
//   leaf g at [slot + g*32]        (32 leaves, 128B apart)
//   root   at [slot + 1024]
//   leaf-flag g at [slot + 2048 + g*32]
#define BAR_SLOT 4096

struct KArgs {
    const float* x;
    const int* srcp;
    const int* dstp;
    int E, n, last;
    const float* W1; const float* b1;
    const float* W2; const float* b2;
    const float* W3; const float* b3;
    const float* fcW; const float* fcb;
    int* deg; int* mark; int* cnt; int* bar;
    int* F2; int2* E3l; int* F1; int2* E2l; int* F0; int2* E1l;
    float* H; float* aggA; float* aggB;
    float* out;
};

// ---------- agent-scope (coherence-point, write-through) STORE helpers ------
// All workspace WRITES go through these (or device atomics), so L2 never
// holds dirty workspace lines -> barrier needs invalidate only, no writeback.
__device__ __forceinline__ void ag_store_i(int* p, int v) {
    __hip_atomic_store(p, v, __ATOMIC_RELAXED, __HIP_MEMORY_SCOPE_AGENT);
}
__device__ __forceinline__ void ag_store_f(float* p, float v) {
    __hip_atomic_store(p, v, __ATOMIC_RELAXED, __HIP_MEMORY_SCOPE_AGENT);
}
__device__ __forceinline__ void ag_store_e(int2* p, int2 v) {
    unsigned long long u = ((unsigned long long)(unsigned)v.y << 32) | (unsigned)v.x;
    __hip_atomic_store((unsigned long long*)p, u, __ATOMIC_RELAXED,
                       __HIP_MEMORY_SCOPE_AGENT);
}

// ---- grid barrier v3: leaf-spread flags + acquire-invalidate ----
// Arrive: leaf RMW -> root RMW -> root broadcasts 32 leaf-flags (distinct
// 128B lines; 16 pollers/line). Visibility: every wave's stores are
// vmcnt-drained at __syncthreads BEFORE the leader's arrive RMW, and all
// stores/atomics hit the coherence point, so flag=1 implies all data is
// globally visible. Reader side: final ACQUIRE load emits the L1/L2
// invalidate so subsequent normal loads refill fresh.
__device__ __forceinline__ void gbar(int* slot) {
    __syncthreads();
    if (threadIdx.x == 0) {
        asm volatile("s_waitcnt vmcnt(0)" ::: "memory");
        const int nb = (int)gridDim.x;
        const int g = blockIdx.x >> 4;
        const int nleaf = (nb + 15) >> 4;
        int* leaf  = slot + g * 32;
        int* root  = slot + 1024;
        int* lflag = slot + 2048 + g * 32;
        int leafSize = nb - (g << 4); if (leafSize > 16) leafSize = 16;
        if (__hip_atomic_fetch_add(leaf, 1, __ATOMIC_RELAXED,
                                   __HIP_MEMORY_SCOPE_AGENT) == leafSize - 1) {
            if (__hip_atomic_fetch_add(root, 1, __ATOMIC_RELAXED,
                                       __HIP_MEMORY_SCOPE_AGENT) == nleaf - 1) {
                asm volatile("" ::: "memory");
                for (int gg = 0; gg < nleaf; ++gg)
                    __hip_atomic_store(slot + 2048 + gg * 32, 1, __ATOMIC_RELAXED,
                                       __HIP_MEMORY_SCOPE_AGENT);
            }
        }
        while (__hip_atomic_load(lflag, __ATOMIC_RELAXED,
                                 __HIP_MEMORY_SCOPE_AGENT) == 0)
            __builtin_amdgcn_s_sleep(4);
        (void)__hip_atomic_load(lflag, __ATOMIC_ACQUIRE,
                                __HIP_MEMORY_SCOPE_AGENT);   // L1/L2 invalidate
    }
    __syncthreads();
}

// ---- row-list GEMM, W staged in LDS; inputs read cached, H stored ag ----
__device__ __forceinline__ void gemm_rows_lds(
    const int* __restrict__ list, int rows,
    const float* __restrict__ Xin, const float* __restrict__ bias,
    const float* __restrict__ W, float* __restrict__ H,
    float (&wsm)[128][128])
{
    const bool active = ((int)blockIdx.x * 4 < rows);   // block-uniform
    if (!active) return;                                // falls to caller's gbar
    const int t = threadIdx.x;
    {
        const float4* W4 = (const float4*)W;
        float4* S4 = (float4*)&wsm[0][0];
        #pragma unroll
        for (int it = 0; it < 16; ++it) S4[it * 256 + t] = W4[it * 256 + t];
    }
    __syncthreads();
    const int wave = t >> 6, lane = t & 63;
    for (int base = blockIdx.x * 4; base < rows; base += gridDim.x * 4) {
        int r = base + wave;
        if (r >= rows) continue;
        int v = list[r];
        size_t off = (size_t)v * NF;

        float x0 = Xin[off + lane];
        float x1 = Xin[off + lane + 64];
        if (bias) {
            x0 = fmaxf(x0 + bias[lane],      0.f);
            x1 = fmaxf(x1 + bias[lane + 64], 0.f);
        }

        float a0 = 0.f, a1 = 0.f;
        #pragma unroll 16
        for (int k = 0; k < 64; ++k) {
            float xk = __shfl(x0, k);
            a0 += xk * wsm[k][lane];
            a1 += xk * wsm[k][lane + 64];
        }
        #pragma unroll 16
        for (int k = 0; k < 64; ++k) {
            float xk = __shfl(x1, k);
            a0 += xk * wsm[k + 64][lane];
            a1 += xk * wsm[k + 64][lane + 64];
        }

        ag_store_f(&H[off + lane],      a0);
        ag_store_f(&H[off + lane + 64], a1);
    }
}

// ---- per-edge hit handlers (mark reads are normal cached loads) ----
__device__ __forceinline__ void p1_hit(const KArgs& a, int d, int i) {
    if (d == a.last) {
        int s = a.srcp[i];
        int p = atomicAdd(&a.cnt[1], 1);
        if (p < CAP_E3) ag_store_e(&a.E3l[p], make_int2(s, d));
        if (!(atomicOr(&a.mark[s], M2) & M2)) {
            int q = atomicAdd(&a.cnt[0], 1);
            if (q < CAP_F2) ag_store_i(&a.F2[q], s);
            int r = atomicAdd(&a.cnt[3], 1);           // self-edge into E2
            if (r < CAP_E2) ag_store_e(&a.E2l[r], make_int2(s, s));
        }
    }
}

__device__ __forceinline__ void p2_hit(const KArgs& a, int d, int i) {
    if (a.mark[d] & M2) {                              // M2 stable during P2
        int s = a.srcp[i];
        int p = atomicAdd(&a.cnt[3], 1);
        if (p < CAP_E2) ag_store_e(&a.E2l[p], make_int2(s, d));
        if (!(atomicOr(&a.mark[s], M1) & M1)) {
            int q = atomicAdd(&a.cnt[2], 1);
            if (q < CAP_F1) ag_store_i(&a.F1[q], s);
            int r = atomicAdd(&a.cnt[5], 1);           // self-edge into E1
            if (r < CAP_E1) ag_store_e(&a.E1l[r], make_int2(s, s));
        }
    }
}

__device__ __forceinline__ void p3_hit(const KArgs& a, int d, int i) {
    if (a.mark[d] & M1) {                              // M1 stable during P3
        int s = a.srcp[i];
        int p = atomicAdd(&a.cnt[5], 1);
        if (p < CAP_E1) ag_store_e(&a.E1l[p], make_int2(s, d));
        if (!(atomicOr(&a.mark[s], M0) & M0)) {
            int q = atomicAdd(&a.cnt[4], 1);
            if (q < CAP_F0) ag_store_i(&a.F0[q], s);
        }
    }
}

__global__ __launch_bounds__(256, 2) void k_fused(KArgs a)
{
    __shared__ float wsm[128][128];   // 64 KB
    const int gtid = blockIdx.x * blockDim.x + threadIdx.x;
    const int gstride = gridDim.x * blockDim.x;
    const int E = a.E;
    int* bar = a.bar;
    const bool vec4 = (((uintptr_t)a.dstp & 15) == 0);
    const int4* d4p = (const int4*)a.dstp;
    const int nq = E >> 2;

    // ---- P1: seed + level-1 scan (dst == last) ----
    if (gtid == 0) {
        if (!(atomicOr(&a.mark[a.last], M2) & M2)) {
            int p = atomicAdd(&a.cnt[0], 1);
            if (p < CAP_F2) ag_store_i(&a.F2[p], a.last);
            int r = atomicAdd(&a.cnt[3], 1);
            if (r < CAP_E2) ag_store_e(&a.E2l[r], make_int2(a.last, a.last));
            int e = atomicAdd(&a.cnt[1], 1);
            if (e < CAP_E3) ag_store_e(&a.E3l[e], make_int2(a.last, a.last));
        }
    }
    if (vec4) {
        for (int q = gtid; q < nq; q += gstride) {
            int4 d4 = d4p[q];
            int i = q << 2;
            p1_hit(a, d4.x, i); p1_hit(a, d4.y, i + 1);
            p1_hit(a, d4.z, i + 2); p1_hit(a, d4.w, i + 3);
        }
        for (int i = (nq << 2) + gtid; i < E; i += gstride) p1_hit(a, a.dstp[i], i);
    } else {
        for (int i = gtid; i < E; i += gstride) p1_hit(a, a.dstp[i], i);
    }
    gbar(&bar[0 * BAR_SLOT]);

    // ---- P2: level-2 scan (M2 -> M1) + self-prop F2 into F1 (+E1 self) ----
    {
        int sc = min(a.cnt[0], CAP_F2);
        for (int i = gtid; i < sc; i += gstride) {
            int v = a.F2[i];
            if (!(atomicOr(&a.mark[v], M1) & M1)) {
                int p = atomicAdd(&a.cnt[2], 1);
                if (p < CAP_F1) ag_store_i(&a.F1[p], v);
                int r = atomicAdd(&a.cnt[5], 1);
                if (r < CAP_E1) ag_store_e(&a.E1l[r], make_int2(v, v));
            }
        }
        if (vec4) {
            for (int q = gtid; q < nq; q += gstride) {
                int4 d4 = d4p[q];
                int i = q << 2;
                p2_hit(a, d4.x, i); p2_hit(a, d4.y, i + 1);
                p2_hit(a, d4.z, i + 2); p2_hit(a, d4.w, i + 3);
            }
            for (int i = (nq << 2) + gtid; i < E; i += gstride) p2_hit(a, a.dstp[i], i);
        } else {
            for (int i = gtid; i < E; i += gstride) p2_hit(a, a.dstp[i], i);
        }
    }
    gbar(&bar[1 * BAR_SLOT]);

    // ---- P3: level-3 scan (M1 -> M0) + self-prop F1 into F0 ----
    {
        int sc = min(a.cnt[2], CAP_F1);
        for (int i = gtid; i < sc; i += gstride) {
            int v = a.F1[i];
            if (!(atomicOr(&a.mark[v], M0) & M0)) {
                int p = atomicAdd(&a.cnt[4], 1);
                if (p < CAP_F0) ag_store_i(&a.F0[p], v);
            }
        }
        if (vec4) {
            for (int q = gtid; q < nq; q += gstride) {
                int4 d4 = d4p[q];
                int i = q << 2;
                p3_hit(a, d4.x, i); p3_hit(a, d4.y, i + 1);
                p3_hit(a, d4.z, i + 2); p3_hit(a, d4.w, i + 3);
            }
            for (int i = (nq << 2) + gtid; i < E; i += gstride) p3_hit(a, a.dstp[i], i);
        } else {
            for (int i = gtid; i < E; i += gstride) p3_hit(a, a.dstp[i], i);
        }
    }
    gbar(&bar[2 * BAR_SLOT]);

    // ---- P4: conditional deg scan + AGG zero-init + GEMM1 (W1 in LDS) ----
    {
        if (vec4) {
            for (int q = gtid; q < nq; q += gstride) {
                int4 d4 = d4p[q];
                if (a.mark[d4.x]) atomicAdd(&a.deg[d4.x], 1);
                if (a.mark[d4.y]) atomicAdd(&a.deg[d4.y], 1);
                if (a.mark[d4.z]) atomicAdd(&a.deg[d4.z], 1);
                if (a.mark[d4.w]) atomicAdd(&a.deg[d4.w], 1);
            }
            for (int i = (nq << 2) + gtid; i < E; i += gstride) {
                int d = a.dstp[i];
                if (a.mark[d]) atomicAdd(&a.deg[d], 1);
            }
        } else {
            for (int i = gtid; i < E; i += gstride) {
                int d = a.dstp[i];
                if (a.mark[d]) atomicAdd(&a.deg[d], 1);
            }
        }
        int f1 = min(a.cnt[2], CAP_F1);
        for (int i = gtid; i < f1 * NF; i += gstride)
            ag_store_f(&a.aggA[(size_t)a.F1[i >> 7] * NF + (i & 127)], 0.f);
        int f2 = min(a.cnt[0], CAP_F2);
        for (int i = gtid; i < f2 * NF; i += gstride)
            ag_store_f(&a.aggB[(size_t)a.F2[i >> 7] * NF + (i & 127)], 0.f);
        gemm_rows_lds(a.F0, min(a.cnt[4], CAP_F0), a.x, nullptr, a.W1, a.H, wsm);
    }
    gbar(&bar[3 * BAR_SLOT]);

    // ---- P5: scatter E1 into aggA ----
    {
        int ecnt = min(a.cnt[5], CAP_E1);
        int grp = gtid >> 7, f = gtid & 127, ngrp = gstride >> 7;
        for (int i = grp; i < ecnt; i += ngrp) {
            int2 e = a.E1l[i];
            float w = rsqrtf(1.f + (float)a.deg[e.x]) *
                      rsqrtf(1.f + (float)a.deg[e.y]);
            atomicAdd(&a.aggA[(size_t)e.y * NF + f],
                      a.H[(size_t)e.x * NF + f] * w);
        }
    }
    gbar(&bar[4 * BAR_SLOT]);

    // ---- P6: GEMM2 on F1 rows: H2 = relu(aggA+b1) @ W2 ----
    gemm_rows_lds(a.F1, min(a.cnt[2], CAP_F1), a.aggA, a.b1, a.W2, a.H, wsm);
    gbar(&bar[5 * BAR_SLOT]);

    // ---- P7: scatter E2 into aggB (grid-wide, ~200 edges) ----
    {
        int ecnt = min(a.cnt[3], CAP_E2);
        int grp = gtid >> 7, f = gtid & 127, ngrp = gstride >> 7;
        for (int i = grp; i < ecnt; i += ngrp) {
            int2 e = a.E2l[i];
            float w = rsqrtf(1.f + (float)a.deg[e.x]) *
                      rsqrtf(1.f + (float)a.deg[e.y]);
            atomicAdd(&a.aggB[(size_t)e.y * NF + f],
                      a.H[(size_t)e.x * NF + f] * w);
        }
    }
    gbar(&bar[6 * BAR_SLOT]);

    // ---- P8 (block 0 only): GEMM3 (~13 rows) + E3 register-reduce + FC ----
    if (blockIdx.x == 0) {
        const int t = threadIdx.x;
        {
            const float4* W4 = (const float4*)a.W3;
            float4* S4 = (float4*)&wsm[0][0];
            #pragma unroll
            for (int it = 0; it < 16; ++it) S4[it * 256 + t] = W4[it * 256 + t];
        }
        __syncthreads();
        const int wave = t >> 6, lane = t & 63;
        int rows = min(a.cnt[0], CAP_F2);
        for (int r = wave; r < rows; r += 4) {
            int v = a.F2[r];
            size_t off = (size_t)v * NF;
            float x0 = fmaxf(a.aggB[off + lane]      + a.b2[lane],      0.f);
            float x1 = fmaxf(a.aggB[off + lane + 64] + a.b2[lane + 64], 0.f);
            float a0 = 0.f, a1 = 0.f;
            #pragma unroll 16
            for (int k = 0; k < 64; ++k) {
                float xk = __shfl(x0, k);
                a0 += xk * wsm[k][lane];
                a1 += xk * wsm[k][lane + 64];
            }
            #pragma unroll 16
            for (int k = 0; k < 64; ++k) {
                float xk = __shfl(x1, k);
                a0 += xk * wsm[k + 64][lane];
                a1 += xk * wsm[k + 64][lane + 64];
            }
            ag_store_f(&a.H[off + lane],      a0);
            ag_store_f(&a.H[off + lane + 64], a1);
        }
        __syncthreads();
        if (t < NF) {
            float dl = rsqrtf(1.f + (float)a.deg[a.last]);
            float acc = 0.f;
            int e3 = min(a.cnt[1], CAP_E3);
            for (int i = 0; i < e3; ++i) {
                int s = a.E3l[i].x;
                acc += rsqrtf(1.f + (float)a.deg[s]) * dl *
                       a.H[(size_t)s * NF + t];
            }
            wsm[0][t] = fmaxf(acc + a.b3[t], 0.f);
        }
        __syncthreads();
        if (t < OUTF) {
            float acc = a.fcb[t];
            #pragma unroll 16
            for (int k = 0; k < NF; ++k) acc += wsm[0][k] * a.fcW[k * OUTF + t];
            a.out[t] = acc;
        }
    }
}

// ---------------------------------------------------------------------------
// Fallback: proven multi-kernel pipeline (used only if coop launch rejected)
// ---------------------------------------------------------------------------

__global__ void k_seed(int* __restrict__ mark, int* __restrict__ F2,
                       int* __restrict__ cnt, int last) {
    if (threadIdx.x == 0) {
        mark[last] = M2;
        F2[0] = last;
        cnt[0] = 1;
    }
}

__global__ void k_mark(const int* __restrict__ src, const int* __restrict__ dst, int E,
                       int* __restrict__ mark, int checkBit, int setBit, int last,
                       int2* __restrict__ Elist, int Ecap, int* __restrict__ eCnt,
                       int* __restrict__ Flist, int Fcap, int* __restrict__ fCnt,
                       const int* __restrict__ selfList, const int* __restrict__ selfCnt,
                       int selfCap)
{
    int i = blockIdx.x * blockDim.x + threadIdx.x;

    if (selfList) {
        int sc = *selfCnt; if (sc > selfCap) sc = selfCap;
        if (i < sc) {
            int v = selfList[i];
            if (!(atomicOr(&mark[v], setBit) & setBit)) {
                int p = atomicAdd(fCnt, 1);
                if (p < Fcap) Flist[p] = v;
            }
        }
    }
    if (i < E) {
        int d = dst[i];
        bool hit = checkBit ? ((mark[d] & checkBit) != 0) : (d == last);
        if (hit) {
            int s = src[i];
            int p = atomicAdd(eCnt, 1);
            if (p < Ecap) Elist[p] = make_int2(s, d);
            if (!(atomicOr(&mark[s], setBit) & setBit)) {
                int q = atomicAdd(fCnt, 1);
                if (q < Fcap) Flist[q] = s;
            }
        }
    }
}

__global__ void k_degm(const int* __restrict__ dst, const int* __restrict__ mark,
                       int* __restrict__ deg, int E) {
    int i = blockIdx.x * blockDim.x + threadIdx.x;
    if (i < E) {
        int d = dst[i];
        if (mark[d]) atomicAdd(&deg[d], 1);
    }
}

__global__ void k_dinvm(const int* __restrict__ mark, const int* __restrict__ deg,
                        float* __restrict__ dinv, int n) {
    int i = blockIdx.x * blockDim.x + threadIdx.x;
    if (i < n && mark[i]) dinv[i] = rsqrtf(1.0f + (float)deg[i]);
}

__global__ __launch_bounds__(256) void k_gemm_rows(
    const int* __restrict__ list, const int* __restrict__ cntPtr, int cap,
    const float* __restrict__ Xin, const float* __restrict__ bias,
    const float* __restrict__ W, const float* __restrict__ dinv,
    const int* __restrict__ mark, int aggBit, int last,
    float* __restrict__ H, float* __restrict__ AGG)
{
    __shared__ float wsm[128][128];
    const int t = threadIdx.x;

    {
        const float4* W4 = (const float4*)W;
        float4* S4 = (float4*)&wsm[0][0];
        #pragma unroll
        for (int it = 0; it < 16; ++it) S4[it * 256 + t] = W4[it * 256 + t];
    }
    __syncthreads();

    int cnt = *cntPtr; if (cnt > cap) cnt = cap;
    const int wave = t >> 6, lane = t & 63;

    for (int base = blockIdx.x * 4; base < cnt; base += gridDim.x * 4) {
        int r = base + wave;
        if (r >= cnt) continue;
        int v = list[r];
        size_t off = (size_t)v * NF;

        float x0, x1;
        if (bias) {
            x0 = fmaxf(Xin[off + lane]      + bias[lane],      0.f);
            x1 = fmaxf(Xin[off + lane + 64] + bias[lane + 64], 0.f);
        } else {
            x0 = Xin[off + lane];
            x1 = Xin[off + lane + 64];
        }

        float a0 = 0.f, a1 = 0.f;
        #pragma unroll 16
        for (int k = 0; k < 64; ++k) {
            float xk = __shfl(x0, k);
            a0 += xk * wsm[k][lane];
            a1 += xk * wsm[k][lane + 64];
        }
        #pragma unroll 16
        for (int k = 0; k < 64; ++k) {
            float xk = __shfl(x1, k);
            a0 += xk * wsm[k + 64][lane];
            a1 += xk * wsm[k + 64][lane + 64];
        }

        H[off + lane]      = a0;
        H[off + lane + 64] = a1;

        bool doAgg = (mark ? ((mark[v] & aggBit) != 0) : false) || (v == last);
        if (doAgg) {
            float di = dinv[v], s2 = di * di;
            AGG[off + lane]      = a0 * s2;
            AGG[off + lane + 64] = a1 * s2;
        }
    }
}

__global__ void k_scat(const int2* __restrict__ list, const int* __restrict__ cntPtr, int cap,
                       const float* __restrict__ dinv, const float* __restrict__ H,
                       float* __restrict__ AGG)
{
    int cnt = *cntPtr; if (cnt > cap) cnt = cap;
    int t = threadIdx.x;
    for (int i = blockIdx.x; i < cnt; i += gridDim.x) {
        int2 e = list[i];
        float w = dinv[e.x] * dinv[e.y];
        atomicAdd(&AGG[(size_t)e.y * NF + t], H[(size_t)e.x * NF + t] * w);
    }
}

__global__ void k_fc(const float* __restrict__ AGG3, const float* __restrict__ b3,
                     const float* __restrict__ fcW, const float* __restrict__ fcb,
                     float* __restrict__ out, int last)
{
    __shared__ float xrow[NF];
    int j = threadIdx.x;
    size_t off = (size_t)last * NF;
    xrow[j]      = fmaxf(AGG3[off + j]      + b3[j],      0.f);
    xrow[j + 64] = fmaxf(AGG3[off + j + 64] + b3[j + 64], 0.f);
    __syncthreads();
    float acc = fcb[j];
    #pragma unroll 16
    for (int k = 0; k < NF; ++k) acc += xrow[k] * fcW[k * OUTF + j];
    out[j] = acc;
}

// ---------------------------------------------------------------------------

extern "C" void kernel_launch(void* const* d_in, const int* in_sizes, int n_in,
                              void* d_out, int out_size, void* d_ws, size_t ws_size,
                              hipStream_t stream)
{
    const float* x    = (const float*)d_in[0];
    const int*   ei   = (const int*)d_in[1];
    const float* W1   = (const float*)d_in[2];
    const float* b1   = (const float*)d_in[3];
    const float* W2   = (const float*)d_in[4];
    const float* b2   = (const float*)d_in[5];
    const float* W3   = (const float*)d_in[6];
    const float* b3   = (const float*)d_in[7];
    const float* fcW  = (const float*)d_in[8];
    const float* fcb  = (const float*)d_in[9];
    float* out = (float*)d_out;

    const int n = in_sizes[0] / NF;       // 50000
    const int E = in_sizes[1] / 2;        // 600000
    const int* src = ei;
    const int* dst = ei + E;
    const int last = n - 1;

    char* wp = (char*)d_ws;
    auto alloc = [&](size_t bytes) -> void* {
        void* r = (void*)wp;
        wp += (bytes + 255) & ~(size_t)255;
        return r;
    };
    // zeroed region: deg | mark | cnt+barriers  (one memset)
    int*   deg  = (int*)alloc((size_t)n * 4);
    int*   mark = (int*)alloc((size_t)n * 4);
    int*   cnt  = (int*)alloc((64 + 8 * BAR_SLOT) * 4);   // counters + 8 barrier slots
    size_t zbytes = (char*)wp - (char*)deg;

    float* dinv = (float*)alloc((size_t)n * 4);      // fallback path only
    int*   F2   = (int*) alloc(CAP_F2 * 4);
    int2*  E3   = (int2*)alloc(CAP_E3 * 8);
    int*   F1   = (int*) alloc(CAP_F1 * 4);
    int2*  E2   = (int2*)alloc(CAP_E2 * 8);
    int*   F0   = (int*) alloc(CAP_F0 * 4);
    int2*  E1   = (int2*)alloc(CAP_E1 * 8);
    float* H    = (float*)alloc((size_t)n * NF * 4);
    float* aggA = (float*)alloc((size_t)n * NF * 4);
    float* aggB = (float*)alloc((size_t)n * NF * 4);

    // ---- single fused kernel (cooperative launch for co-residency) ----
    static int coopState = -2;   // -2 untested, -1 unsupported, >0 grid size
    if (coopState != -1) {
        if (coopState == -2) {
            int perCU = 0;
            if (hipOccupancyMaxActiveBlocksPerMultiprocessor(&perCU, k_fused, 256, 0)
                    != hipSuccess || perCU < 1)
                perCU = 1;
            long g = (long)perCU * 256;   // 256 CUs on MI355X
            if (g > 512) g = 512;         // 64KB LDS -> 2 blocks/CU max
            coopState = (int)g;
        }
        KArgs ha;
        ha.x = x; ha.srcp = src; ha.dstp = dst;
        ha.E = E; ha.n = n; ha.last = last;
        ha.W1 = W1; ha.b1 = b1; ha.W2 = W2; ha.b2 = b2;
        ha.W3 = W3; ha.b3 = b3; ha.fcW = fcW; ha.fcb = fcb;
        ha.deg = deg; ha.mark = mark; ha.cnt = cnt; ha.bar = cnt + 64;
        ha.F2 = F2; ha.E3l = E3; ha.F1 = F1; ha.E2l = E2; ha.F0 = F0; ha.E1l = E1;
        ha.H = H; ha.aggA = aggA; ha.aggB = aggB; ha.out = out;

        hipMemsetAsync(deg, 0, zbytes, stream);   // zeros deg, mark, cnt, barriers
        void* params[1] = { (void*)&ha };
        hipError_t err = hipLaunchCooperativeKernel(k_fused, dim3(coopState), dim3(256),
                                                    params, 0u, stream);
        if (err == hipSuccess) return;
        coopState = -1;          // coop not available; use fallback
        (void)hipGetLastError();
    }

    // ---- fallback: original multi-kernel pipeline ----
    const int B  = 256;
    const int EB = (E + B - 1) / B;
    const int NB = (n + B - 1) / B;

    hipMemsetAsync(deg, 0, zbytes, stream);
    k_seed<<<1, 64, 0, stream>>>(mark, F2, cnt, last);

    k_mark<<<EB, B, 0, stream>>>(src, dst, E, mark, 0,  M2, last,
                                 E3, CAP_E3, &cnt[1], F2, CAP_F2, &cnt[0],
                                 nullptr, nullptr, 0);
    k_mark<<<EB, B, 0, stream>>>(src, dst, E, mark, M2, M1, last,
                                 E2, CAP_E2, &cnt[3], F1, CAP_F1, &cnt[2],
                                 F2, &cnt[0], CAP_F2);
    k_mark<<<EB, B, 0, stream>>>(src, dst, E, mark, M1, M0, last,
                                 E1, CAP_E1, &cnt[5], F0, CAP_F0, &cnt[4],
                                 F1, &cnt[2], CAP_F1);

    k_degm <<<EB, B, 0, stream>>>(dst, mark, deg, E);
    k_dinvm<<<NB, B, 0, stream>>>(mark, deg, dinv, n);

    k_gemm_rows<<<384, B, 0, stream>>>(F0, &cnt[4], CAP_F0, x, nullptr, W1,
                                       dinv, mark, M1, -1, H, aggA);
    k_scat<<<2048, 128, 0, stream>>>(E1, &cnt[5], CAP_E1, dinv, H, aggA);

    k_gemm_rows<<<384, B, 0, stream>>>(F1, &cnt[2], CAP_F1, aggA, b1, W2,
                                       dinv, mark, M2, -1, H, aggB);
    k_scat<<<2048, 128, 0, stream>>>(E2, &cnt[3], CAP_E2, dinv, H, aggB);

    k_gemm_rows<<<384, B, 0, stream>>>(F2, &cnt[0], CAP_F2, aggB, b2, W3,
                                       dinv, nullptr, 0, last, H, aggA);
    k_scat<<<2048, 128, 0, stream>>>(E3, &cnt[1], CAP_E3, dinv, H, aggA);

    k_fc<<<1, 64, 0, stream>>>(aggA, b3, fcW, fcb, out, last);
}

// Round 7
// 202.639 us; speedup vs baseline: 1.1519x; 1.1519x over previous
//
#include <hip/hip_runtime.h>

#define NF 128
#define OUTF 64

// mark bits
#define M2 1
#define M1 2
#define M0 4

// capacity caps (expected ~13 / ~190 / ~2600 nodes; huge slack)
#define CAP_F2 2048
#define CAP_E3 4096
#define CAP_F1 32768
#define CAP_E2 65536
#define CAP_F0 131072
#define CAP_E1 262144

// cnt[0]=F2, cnt[1]=E3, cnt[2]=F1, cnt[3]=E2, cnt[4]=F0, cnt[5]=E1
// bar = cnt+64: per-barrier slot of 4096 ints (16KB):
//   leaf g at [slot+g*32], root [slot+1024], leaf-flag g [slot+2048+g*32]
#define BAR_SLOT 4096
#define NBLK 256          // 256 blocks x 256 thr; 64KB LDS -> <=2/CU -> always co-resident

struct KArgs {
    const float* x;
    const int* srcp;
    const int* dstp;
    int E, n, last;
    const float* W1; const float* b1;
    const float* W2; const float* b2;
    const float* W3; const float* b3;
    const float* fcW; const float* fcb;
    int* deg; int* mark; int* cnt; int* bar;
    int* F2; int2* E3l; int* F1; int2* E2l; int* F0; int2* E1l;
    float* H1; float* H2;
    float* out;
};

// ---------- agent-scope (coherence-point, write-through) STORE helpers ------
// All cross-block workspace WRITES go through these (or device atomics), so
// L2 never holds dirty workspace lines -> barrier needs invalidate only.
__device__ __forceinline__ void ag_store_i(int* p, int v) {
    __hip_atomic_store(p, v, __ATOMIC_RELAXED, __HIP_MEMORY_SCOPE_AGENT);
}
__device__ __forceinline__ void ag_store_f(float* p, float v) {
    __hip_atomic_store(p, v, __ATOMIC_RELAXED, __HIP_MEMORY_SCOPE_AGENT);
}
__device__ __forceinline__ void ag_store_e(int2* p, int2 v) {
    unsigned long long u = ((unsigned long long)(unsigned)v.y << 32) | (unsigned)v.x;
    __hip_atomic_store((unsigned long long*)p, u, __ATOMIC_RELAXED,
                       __HIP_MEMORY_SCOPE_AGENT);
}

// ---- grid barrier: two-level arrive, leaf-spread flags, acquire-invalidate ----
__device__ __forceinline__ void gbar(int* slot) {
    __syncthreads();
    if (threadIdx.x == 0) {
        asm volatile("s_waitcnt vmcnt(0)" ::: "memory");
        const int nb = (int)gridDim.x;
        const int g = blockIdx.x >> 4;
        const int nleaf = (nb + 15) >> 4;
        int* leaf  = slot + g * 32;
        int* root  = slot + 1024;
        int* lflag = slot + 2048 + g * 32;
        int leafSize = nb - (g << 4); if (leafSize > 16) leafSize = 16;
        if (__hip_atomic_fetch_add(leaf, 1, __ATOMIC_RELAXED,
                                   __HIP_MEMORY_SCOPE_AGENT) == leafSize - 1) {
            if (__hip_atomic_fetch_add(root, 1, __ATOMIC_RELAXED,
                                       __HIP_MEMORY_SCOPE_AGENT) == nleaf - 1) {
                asm volatile("" ::: "memory");
                for (int gg = 0; gg < nleaf; ++gg)
                    __hip_atomic_store(slot + 2048 + gg * 32, 1, __ATOMIC_RELAXED,
                                       __HIP_MEMORY_SCOPE_AGENT);
            }
        }
        while (__hip_atomic_load(lflag, __ATOMIC_RELAXED,
                                 __HIP_MEMORY_SCOPE_AGENT) == 0)
            __builtin_amdgcn_s_sleep(2);
        (void)__hip_atomic_load(lflag, __ATOMIC_ACQUIRE,
                                __HIP_MEMORY_SCOPE_AGENT);   // L1/L2 invalidate
    }
    __syncthreads();
}

// ---- per-edge hit handlers ----
__device__ __forceinline__ void p1_hit(const KArgs& a, int d, int i) {
    if (d == a.last) {
        int s = a.srcp[i];
        int p = atomicAdd(&a.cnt[1], 1);
        if (p < CAP_E3) ag_store_e(&a.E3l[p], make_int2(s, d));
        if (!(atomicOr(&a.mark[s], M2) & M2)) {
            int q = atomicAdd(&a.cnt[0], 1);
            if (q < CAP_F2) ag_store_i(&a.F2[q], s);
            int r = atomicAdd(&a.cnt[3], 1);            // self-edge into E2
            if (r < CAP_E2) ag_store_e(&a.E2l[r], make_int2(s, s));
        }
    }
}

__device__ __forceinline__ void p2_hit(const KArgs& a, int d, int i) {
    if (a.mark[d] & M2) {                               // M2 final during P2
        int s = a.srcp[i];
        int p = atomicAdd(&a.cnt[3], 1);
        if (p < CAP_E2) ag_store_e(&a.E2l[p], make_int2(s, d));
        if (!(atomicOr(&a.mark[s], M1) & M1)) {
            int q = atomicAdd(&a.cnt[2], 1);
            if (q < CAP_F1) ag_store_i(&a.F1[q], s);
            int r = atomicAdd(&a.cnt[5], 1);            // self-edge into E1
            if (r < CAP_E1) ag_store_e(&a.E1l[r], make_int2(s, s));
        }
    }
}

__device__ __forceinline__ void p3_hit(const KArgs& a, int d, int i) {
    if (a.mark[d] & M1) {                               // M1 final during P3
        int s = a.srcp[i];
        int p = atomicAdd(&a.cnt[5], 1);
        if (p < CAP_E1) ag_store_e(&a.E1l[p], make_int2(s, d));
        if (!(atomicOr(&a.mark[s], M0) & M0)) {
            int q = atomicAdd(&a.cnt[4], 1);
            if (q < CAP_F0) ag_store_i(&a.F0[q], s);
        }
    }
}

__global__ __launch_bounds__(256, 2) void k_fused(KArgs a)
{
    __shared__ float wsm[128][128];   // 64 KB: W staging; last row reused by FC
    const int gtid = blockIdx.x * blockDim.x + threadIdx.x;
    const int gstride = gridDim.x * blockDim.x;
    const int t = threadIdx.x;
    const int wave = t >> 6, lane = t & 63;
    const int E = a.E;
    int* bar = a.bar;
    const bool vec4 = (((uintptr_t)a.dstp & 15) == 0);
    const int4* d4p = (const int4*)a.dstp;
    const int nq = E >> 2;

    // ================= P1: seed + level-1 scan (dst == last) =================
    if (gtid == 0) {
        if (!(atomicOr(&a.mark[a.last], M2) & M2)) {
            int p = atomicAdd(&a.cnt[0], 1);
            if (p < CAP_F2) ag_store_i(&a.F2[p], a.last);
            int r = atomicAdd(&a.cnt[3], 1);
            if (r < CAP_E2) ag_store_e(&a.E2l[r], make_int2(a.last, a.last));
            int e = atomicAdd(&a.cnt[1], 1);
            if (e < CAP_E3) ag_store_e(&a.E3l[e], make_int2(a.last, a.last));
        }
    }
    if (vec4) {
        for (int q = gtid; q < nq; q += gstride) {
            int4 d4 = d4p[q];
            int i = q << 2;
            p1_hit(a, d4.x, i); p1_hit(a, d4.y, i + 1);
            p1_hit(a, d4.z, i + 2); p1_hit(a, d4.w, i + 3);
        }
        for (int i = (nq << 2) + gtid; i < E; i += gstride) p1_hit(a, a.dstp[i], i);
    } else {
        for (int i = gtid; i < E; i += gstride) p1_hit(a, a.dstp[i], i);
    }
    gbar(&bar[0 * BAR_SLOT]);

    // ====== P2: level-2 scan (M2 -> M1) + self-prop F2 -> F1 (+E1 self) ======
    {
        int sc = min(a.cnt[0], CAP_F2);
        for (int i = gtid; i < sc; i += gstride) {
            int v = a.F2[i];
            if (!(atomicOr(&a.mark[v], M1) & M1)) {
                int p = atomicAdd(&a.cnt[2], 1);
                if (p < CAP_F1) ag_store_i(&a.F1[p], v);
                int r = atomicAdd(&a.cnt[5], 1);
                if (r < CAP_E1) ag_store_e(&a.E1l[r], make_int2(v, v));
            }
        }
        if (vec4) {
            for (int q = gtid; q < nq; q += gstride) {
                int4 d4 = d4p[q];
                int i = q << 2;
                p2_hit(a, d4.x, i); p2_hit(a, d4.y, i + 1);
                p2_hit(a, d4.z, i + 2); p2_hit(a, d4.w, i + 3);
            }
            for (int i = (nq << 2) + gtid; i < E; i += gstride) p2_hit(a, a.dstp[i], i);
        } else {
            for (int i = gtid; i < E; i += gstride) p2_hit(a, a.dstp[i], i);
        }
    }
    gbar(&bar[1 * BAR_SLOT]);

    // ====== P3: level-3 scan (M1 -> M0) + self-prop F1 -> F0 ======
    {
        int sc = min(a.cnt[2], CAP_F1);
        for (int i = gtid; i < sc; i += gstride) {
            int v = a.F1[i];
            if (!(atomicOr(&a.mark[v], M0) & M0)) {
                int p = atomicAdd(&a.cnt[4], 1);
                if (p < CAP_F0) ag_store_i(&a.F0[p], v);
            }
        }
        if (vec4) {
            for (int q = gtid; q < nq; q += gstride) {
                int4 d4 = d4p[q];
                int i = q << 2;
                p3_hit(a, d4.x, i); p3_hit(a, d4.y, i + 1);
                p3_hit(a, d4.z, i + 2); p3_hit(a, d4.w, i + 3);
            }
            for (int i = (nq << 2) + gtid; i < E; i += gstride) p3_hit(a, a.dstp[i], i);
        } else {
            for (int i = gtid; i < E; i += gstride) p3_hit(a, a.dstp[i], i);
        }
    }
    gbar(&bar[2 * BAR_SLOT]);

    // ====== P4: deg scan (marked dsts) + GEMM1: H1 = x @ W1 on F0 rows ======
    {
        if (vec4) {
            for (int q = gtid; q < nq; q += gstride) {
                int4 d4 = d4p[q];
                if (a.mark[d4.x]) atomicAdd(&a.deg[d4.x], 1);
                if (a.mark[d4.y]) atomicAdd(&a.deg[d4.y], 1);
                if (a.mark[d4.z]) atomicAdd(&a.deg[d4.z], 1);
                if (a.mark[d4.w]) atomicAdd(&a.deg[d4.w], 1);
            }
            for (int i = (nq << 2) + gtid; i < E; i += gstride) {
                int d = a.dstp[i];
                if (a.mark[d]) atomicAdd(&a.deg[d], 1);
            }
        } else {
            for (int i = gtid; i < E; i += gstride) {
                int d = a.dstp[i];
                if (a.mark[d]) atomicAdd(&a.deg[d], 1);
            }
        }
        int rows = min(a.cnt[4], CAP_F0);
        if ((int)blockIdx.x * 4 < rows) {
            {   // stage W1
                const float4* W4 = (const float4*)a.W1;
                float4* S4 = (float4*)&wsm[0][0];
                #pragma unroll
                for (int it = 0; it < 16; ++it) S4[it * 256 + t] = W4[it * 256 + t];
            }
            __syncthreads();
            for (int base = blockIdx.x * 4; base < rows; base += gridDim.x * 4) {
                int r = base + wave;
                if (r >= rows) continue;
                int v = a.F0[r];
                size_t off = (size_t)v * NF;
                float x0 = a.x[off + lane];
                float x1 = a.x[off + lane + 64];
                float a0 = 0.f, a1 = 0.f;
                #pragma unroll 16
                for (int k = 0; k < 64; ++k) {
                    float xk = __shfl(x0, k);
                    a0 += xk * wsm[k][lane];
                    a1 += xk * wsm[k][lane + 64];
                }
                #pragma unroll 16
                for (int k = 0; k < 64; ++k) {
                    float xk = __shfl(x1, k);
                    a0 += xk * wsm[k + 64][lane];
                    a1 += xk * wsm[k + 64][lane + 64];
                }
                ag_store_f(&a.H1[off + lane],      a0);
                ag_store_f(&a.H1[off + lane + 64], a1);
            }
        }
    }
    gbar(&bar[3 * BAR_SLOT]);

    // ====== P5: GEMM2 with fused E1-gather input (registers, no agg array) ====
    // row d in F1: xin = sum_{(s,d) in E1} dinv[s]*dinv[d]*H1[s]; H2 = relu(xin+b1)@W2
    {
        int rows = min(a.cnt[2], CAP_F1);
        int e1cnt = min(a.cnt[5], CAP_E1);
        if ((int)blockIdx.x * 4 < rows) {
            {   // stage W2
                const float4* W4 = (const float4*)a.W2;
                float4* S4 = (float4*)&wsm[0][0];
                #pragma unroll
                for (int it = 0; it < 16; ++it) S4[it * 256 + t] = W4[it * 256 + t];
            }
            __syncthreads();
            for (int base = blockIdx.x * 4; base < rows; base += gridDim.x * 4) {
                int r = base + wave;
                if (r >= rows) continue;          // uniform per wave
                int v = a.F1[r];
                float dv = rsqrtf(1.f + (float)a.deg[v]);
                float x0 = 0.f, x1 = 0.f;
                for (int bb = 0; bb < e1cnt; bb += 64) {
                    int idx = bb + lane;
                    int sx = 0, sy = -1;
                    if (idx < e1cnt) { int2 e = a.E1l[idx]; sx = e.x; sy = e.y; }
                    unsigned long long m = __ballot(sy == v);
                    while (m) {
                        int j = __ffsll(m) - 1;
                        m &= m - 1;
                        int s = __shfl(sx, j);
                        float w = rsqrtf(1.f + (float)a.deg[s]) * dv;
                        size_t so = (size_t)s * NF;
                        x0 += w * a.H1[so + lane];
                        x1 += w * a.H1[so + lane + 64];
                    }
                }
                x0 = fmaxf(x0 + a.b1[lane],      0.f);
                x1 = fmaxf(x1 + a.b1[lane + 64], 0.f);
                float a0 = 0.f, a1 = 0.f;
                #pragma unroll 16
                for (int k = 0; k < 64; ++k) {
                    float xk = __shfl(x0, k);
                    a0 += xk * wsm[k][lane];
                    a1 += xk * wsm[k][lane + 64];
                }
                #pragma unroll 16
                for (int k = 0; k < 64; ++k) {
                    float xk = __shfl(x1, k);
                    a0 += xk * wsm[k + 64][lane];
                    a1 += xk * wsm[k + 64][lane + 64];
                }
                size_t off = (size_t)v * NF;
                ag_store_f(&a.H2[off + lane],      a0);
                ag_store_f(&a.H2[off + lane + 64], a1);
            }
        }
    }
    gbar(&bar[4 * BAR_SLOT]);

    // ====== P6 (block 0): E2-gather + GEMM3 + E3-reduce + FC ======
    if (blockIdx.x == 0) {
        {   // stage W3
            const float4* W4 = (const float4*)a.W3;
            float4* S4 = (float4*)&wsm[0][0];
            #pragma unroll
            for (int it = 0; it < 16; ++it) S4[it * 256 + t] = W4[it * 256 + t];
        }
        __syncthreads();
        int rows = min(a.cnt[0], CAP_F2);
        int e2cnt = min(a.cnt[3], CAP_E2);
        for (int r = wave; r < rows; r += 4) {
            int v = a.F2[r];
            float dv = rsqrtf(1.f + (float)a.deg[v]);
            float x0 = 0.f, x1 = 0.f;
            for (int bb = 0; bb < e2cnt; bb += 64) {
                int idx = bb + lane;
                int sx = 0, sy = -1;
                if (idx < e2cnt) { int2 e = a.E2l[idx]; sx = e.x; sy = e.y; }
                unsigned long long m = __ballot(sy == v);
                while (m) {
                    int j = __ffsll(m) - 1;
                    m &= m - 1;
                    int s = __shfl(sx, j);
                    float w = rsqrtf(1.f + (float)a.deg[s]) * dv;
                    size_t so = (size_t)s * NF;
                    x0 += w * a.H2[so + lane];
                    x1 += w * a.H2[so + lane + 64];
                }
            }
            x0 = fmaxf(x0 + a.b2[lane],      0.f);
            x1 = fmaxf(x1 + a.b2[lane + 64], 0.f);
            float a0 = 0.f, a1 = 0.f;
            #pragma unroll 16
            for (int k = 0; k < 64; ++k) {
                float xk = __shfl(x0, k);
                a0 += xk * wsm[k][lane];
                a1 += xk * wsm[k][lane + 64];
            }
            #pragma unroll 16
            for (int k = 0; k < 64; ++k) {
                float xk = __shfl(x1, k);
                a0 += xk * wsm[k + 64][lane];
                a1 += xk * wsm[k + 64][lane + 64];
            }
            size_t off = (size_t)v * NF;
            // H3 stored into H1 buffer (H1 dead now); same-block reads only
            a.H1[off + lane]      = a0;
            a.H1[off + lane + 64] = a1;
        }
        __syncthreads();
        if (t < NF) {
            float dl = rsqrtf(1.f + (float)a.deg[a.last]);
            float acc = 0.f;
            int e3cnt = min(a.cnt[1], CAP_E3);
            for (int i = 0; i < e3cnt; ++i) {
                int s = a.E3l[i].x;
                acc += rsqrtf(1.f + (float)a.deg[s]) * dl * a.H1[(size_t)s * NF + t];
            }
            wsm[0][t] = fmaxf(acc + a.b3[t], 0.f);
        }
        __syncthreads();
        if (t < OUTF) {
            float acc = a.fcb[t];
            #pragma unroll 16
            for (int k = 0; k < NF; ++k) acc += wsm[0][k] * a.fcW[k * OUTF + t];
            a.out[t] = acc;
        }
    }
}

// ---------------------------------------------------------------------------

extern "C" void kernel_launch(void* const* d_in, const int* in_sizes, int n_in,
                              void* d_out, int out_size, void* d_ws, size_t ws_size,
                              hipStream_t stream)
{
    const float* x    = (const float*)d_in[0];
    const int*   ei   = (const int*)d_in[1];
    const float* W1   = (const float*)d_in[2];
    const float* b1   = (const float*)d_in[3];
    const float* W2   = (const float*)d_in[4];
    const float* b2   = (const float*)d_in[5];
    const float* W3   = (const float*)d_in[6];
    const float* b3   = (const float*)d_in[7];
    const float* fcW  = (const float*)d_in[8];
    const float* fcb  = (const float*)d_in[9];
    float* out = (float*)d_out;

    const int n = in_sizes[0] / NF;       // 50000
    const int E = in_sizes[1] / 2;        // 600000
    const int* src = ei;
    const int* dst = ei + E;
    const int last = n - 1;

    char* wp = (char*)d_ws;
    auto alloc = [&](size_t bytes) -> void* {
        void* r = (void*)wp;
        wp += (bytes + 255) & ~(size_t)255;
        return r;
    };
    // zeroed region: deg | mark | cnt+barriers  (one memset)
    int*   deg  = (int*)alloc((size_t)n * 4);
    int*   mark = (int*)alloc((size_t)n * 4);
    int*   cnt  = (int*)alloc((64 + 8 * BAR_SLOT) * 4);
    size_t zbytes = (char*)wp - (char*)deg;

    int*   F2   = (int*) alloc(CAP_F2 * 4);
    int2*  E3   = (int2*)alloc(CAP_E3 * 8);
    int*   F1   = (int*) alloc(CAP_F1 * 4);
    int2*  E2   = (int2*)alloc(CAP_E2 * 8);
    int*   F0   = (int*) alloc(CAP_F0 * 4);
    int2*  E1   = (int2*)alloc(CAP_E1 * 8);
    float* H1   = (float*)alloc((size_t)n * NF * 4);
    float* H2   = (float*)alloc((size_t)n * NF * 4);

    KArgs ha;
    ha.x = x; ha.srcp = src; ha.dstp = dst;
    ha.E = E; ha.n = n; ha.last = last;
    ha.W1 = W1; ha.b1 = b1; ha.W2 = W2; ha.b2 = b2;
    ha.W3 = W3; ha.b3 = b3; ha.fcW = fcW; ha.fcb = fcb;
    ha.deg = deg; ha.mark = mark; ha.cnt = cnt; ha.bar = cnt + 64;
    ha.F2 = F2; ha.E3l = E3; ha.F1 = F1; ha.E2l = E2; ha.F0 = F0; ha.E1l = E1;
    ha.H1 = H1; ha.H2 = H2; ha.out = out;

    hipMemsetAsync(deg, 0, zbytes, stream);   // zeros deg, mark, cnt, barriers

    // Plain (graph-capturable) launch. Co-residency by construction:
    // 64KB LDS -> 2 blocks/CU max; NBLK=256 <= 256 CUs * 2 = 512 capacity.
    k_fused<<<dim3(NBLK), dim3(256), 0, stream>>>(ha);
}